// Round 1
// baseline (334.763 us; speedup 1.0000x reference)
//
#include <hip/hip_runtime.h>

// DEQ fused kernel: out = relu^{(30)}(z Wz^T + inj) @ Wd^T + bd, inj = x Ux^T + b
//
// Layout trick: compute D[n][m] = sum_k Wz[n][k] * Z^T[k][m] with Wz as the MFMA
// A-operand (register-resident, iteration-invariant). The D fragment's register
// axis is n, which is exactly the k-axis of the next iteration's B operand, so
// storing to LDS row-major z[m][n] gives packed ds_write_b64 on the store side
// AND contiguous ds_read_b128 on the next iteration's load side. No transpose.

typedef __attribute__((ext_vector_type(8))) __bf16 bf16x8;
typedef __attribute__((ext_vector_type(4))) __bf16 bf16x4;
typedef __attribute__((ext_vector_type(4))) float  floatx4;

#define MFMA16(a, b, c) __builtin_amdgcn_mfma_f32_16x16x32_bf16((a), (b), (c), 0, 0, 0)

static constexpr int kBsz = 262144;
static constexpr int kTM  = 64;    // batch rows per block

__device__ __forceinline__ bf16x8 cvt_bf16x8(float4 a, float4 b) {
  bf16x8 r;
  r[0] = (__bf16)a.x; r[1] = (__bf16)a.y; r[2] = (__bf16)a.z; r[3] = (__bf16)a.w;
  r[4] = (__bf16)b.x; r[5] = (__bf16)b.y; r[6] = (__bf16)b.z; r[7] = (__bf16)b.w;
  return r;
}

__global__ void __launch_bounds__(256) deq_fused(
    const float* __restrict__ x,    // [B,64]
    const float* __restrict__ Wz,   // [128,128]
    const float* __restrict__ Ux,   // [128,64]
    const float* __restrict__ bvec, // [128]
    const float* __restrict__ Wd,   // [64,128]
    const float* __restrict__ bd,   // [64]
    const int*  __restrict__ n_iters_p,
    float* __restrict__ out)        // [B,64]
{
  // double-buffered z tile, row-major [m][n], stride 136 bf16 = 272 B
  // (272 B = 68 words -> 4m mod 32 bank spread, 2-way conflicts only = free)
  __shared__ __align__(16) __bf16 zl[2][kTM][136];

  const int tid  = threadIdx.x;
  const int lane = tid & 63;
  const int wv   = tid >> 6;   // 0..3
  const int wn   = wv & 1;     // n-half: hid units [64*wn, 64*wn+64)
  const int wm   = wv >> 1;    // m-half: rows [32*wm, 32*wm+32) of the block tile
  const int l15  = lane & 15;
  const int quad = lane >> 4;  // 0..3
  const int row0 = blockIdx.x * kTM;
  const int iters = *n_iters_p;

  // ---- Wz as A-fragments (iteration-invariant, register-resident) ----
  // A[n][k]: n = 64*wn + 16*nt + l15, k = 32*ks + 8*quad + j
  bf16x8 awz[4][4];
#pragma unroll
  for (int nt = 0; nt < 4; ++nt) {
    const int n = 64 * wn + 16 * nt + l15;
#pragma unroll
    for (int ks = 0; ks < 4; ++ks) {
      const float4* p = (const float4*)(Wz + n * 128 + 32 * ks + 8 * quad);
      awz[nt][ks] = cvt_bf16x8(p[0], p[1]);
    }
  }

  // ---- inj^T in C/D layout: inj[nt][mt], reg i -> n = 64wn+16nt+4quad+i, col -> m ----
  floatx4 inj[4][2];
#pragma unroll
  for (int nt = 0; nt < 4; ++nt) {
    const float4 bv = *(const float4*)(bvec + 64 * wn + 16 * nt + 4 * quad);
#pragma unroll
    for (int mt = 0; mt < 2; ++mt) {
      floatx4 v = {bv.x, bv.y, bv.z, bv.w};
      inj[nt][mt] = v;
    }
  }
  {
    // Ux as A-frags (K=64 -> 2 k-steps)
    bf16x8 aux[4][2];
#pragma unroll
    for (int nt = 0; nt < 4; ++nt) {
      const int n = 64 * wn + 16 * nt + l15;
#pragma unroll
      for (int ks = 0; ks < 2; ++ks) {
        const float4* p = (const float4*)(Ux + n * 64 + 32 * ks + 8 * quad);
        aux[nt][ks] = cvt_bf16x8(p[0], p[1]);
      }
    }
    // x^T as B-frags: B[k][m] = x[m][k]
#pragma unroll
    for (int mt = 0; mt < 2; ++mt) {
      const int m = row0 + 32 * wm + 16 * mt + l15;
#pragma unroll
      for (int ks = 0; ks < 2; ++ks) {
        const float4* p = (const float4*)(x + m * 64 + 32 * ks + 8 * quad);
        const bf16x8 bx = cvt_bf16x8(p[0], p[1]);
#pragma unroll
        for (int nt = 0; nt < 4; ++nt)
          inj[nt][mt] = MFMA16(aux[nt][ks], bx, inj[nt][mt]);
      }
    }
  }

  // ---- z1 = relu(inj) (z0 = 0) -> buffer 0, packed b64 writes ----
#pragma unroll
  for (int mt = 0; mt < 2; ++mt) {
    const int ml = 32 * wm + 16 * mt + l15;
#pragma unroll
    for (int nt = 0; nt < 4; ++nt) {
      bf16x4 z4;
#pragma unroll
      for (int i = 0; i < 4; ++i) z4[i] = (__bf16)fmaxf(inj[nt][mt][i], 0.0f);
      *(bf16x4*)&zl[0][ml][64 * wn + 16 * nt + 4 * quad] = z4;
    }
  }

  // ---- fixed-point loop: 1 barrier per iteration (double buffer) ----
  int pb = 0;
  for (int t = 0; t < iters - 1; ++t) {
    __syncthreads();
    // prefetch Z^T B-frags: B[k][m], k contiguous -> ds_read_b128
    bf16x8 bz[2][4];
#pragma unroll
    for (int mt = 0; mt < 2; ++mt) {
      const int ml = 32 * wm + 16 * mt + l15;
#pragma unroll
      for (int ks = 0; ks < 4; ++ks)
        bz[mt][ks] = *(const bf16x8*)&zl[pb][ml][32 * ks + 8 * quad];
    }
    const int nb = pb ^ 1;
#pragma unroll
    for (int mt = 0; mt < 2; ++mt) {
      const int ml = 32 * wm + 16 * mt + l15;
#pragma unroll
      for (int nt = 0; nt < 4; ++nt) {
        floatx4 acc = inj[nt][mt];
#pragma unroll
        for (int ks = 0; ks < 4; ++ks)
          acc = MFMA16(awz[nt][ks], bz[mt][ks], acc);
        bf16x4 z4;
#pragma unroll
        for (int i = 0; i < 4; ++i) z4[i] = (__bf16)fmaxf(acc[i], 0.0f);
        // reg axis i is consecutive n -> one ds_write_b64
        *(bf16x4*)&zl[nb][ml][64 * wn + 16 * nt + 4 * quad] = z4;
      }
    }
    pb = nb;
  }
  __syncthreads();

  // ---- decoder: D[o][m] = sum_k Wd[o][k] Z^T[k][m] + bd ----
  bf16x8 awd[2][4];
#pragma unroll
  for (int ot = 0; ot < 2; ++ot) {
    const int o = 32 * wn + 16 * ot + l15;
#pragma unroll
    for (int ks = 0; ks < 4; ++ks) {
      const float4* p = (const float4*)(Wd + o * 128 + 32 * ks + 8 * quad);
      awd[ot][ks] = cvt_bf16x8(p[0], p[1]);
    }
  }
#pragma unroll
  for (int mt = 0; mt < 2; ++mt) {
    const int ml = 32 * wm + 16 * mt + l15;
    bf16x8 bz[4];
#pragma unroll
    for (int ks = 0; ks < 4; ++ks)
      bz[ks] = *(const bf16x8*)&zl[pb][ml][32 * ks + 8 * quad];
#pragma unroll
    for (int ot = 0; ot < 2; ++ot) {
      const float4 bv = *(const float4*)(bd + 32 * wn + 16 * ot + 4 * quad);
      floatx4 acc = {bv.x, bv.y, bv.z, bv.w};
#pragma unroll
      for (int ks = 0; ks < 4; ++ks)
        acc = MFMA16(awd[ot][ks], bz[ks], acc);
      // reg i -> consecutive o: one dwordx4 global store
      float4 ov;
      ov.x = acc[0]; ov.y = acc[1]; ov.z = acc[2]; ov.w = acc[3];
      *(float4*)(out + (size_t)(row0 + ml) * 64 + 32 * wn + 16 * ot + 4 * quad) = ov;
    }
  }
}

extern "C" void kernel_launch(void* const* d_in, const int* in_sizes, int n_in,
                              void* d_out, int out_size, void* d_ws, size_t ws_size,
                              hipStream_t stream) {
  const float* x  = (const float*)d_in[0];
  const float* Wz = (const float*)d_in[1];
  const float* Ux = (const float*)d_in[2];
  const float* b  = (const float*)d_in[3];
  const float* Wd = (const float*)d_in[4];
  const float* bd = (const float*)d_in[5];
  const int* n_it = (const int*)d_in[6];
  float* out = (float*)d_out;
  (void)in_sizes; (void)n_in; (void)d_ws; (void)ws_size; (void)out_size;

  dim3 grid(kBsz / kTM);  // 4096 blocks
  deq_fused<<<grid, 256, 0, stream>>>(x, Wz, Ux, b, Wd, bd, n_it, out);
}